// Round 3
// baseline (842.353 us; speedup 1.0000x reference)
//
#include <hip/hip_runtime.h>
#include <hip/hip_bf16.h>

#define L2E   1.44269504088896340736f
#define SQRT2 1.41421356237309504880f

#define T_LEN 32000
#define BATCH 8
#define NCH   9
#define KCH   32       // chunks
#define CL    1000     // chunk length (KCH*CL == T_LEN)
#define WU    128      // layer-0 warm-up
#define WUF   136      // layer-1 warm-up (71 tiles of 16: 1136 = WUF + CL)
#define NTIL  71
#define MROWS (T_LEN*BATCH)   // 256000 rows per stack

typedef __bf16 bf16x8 __attribute__((ext_vector_type(8)));
typedef float  f32x4  __attribute__((ext_vector_type(4)));
typedef float  f32x2  __attribute__((ext_vector_type(2)));

// ---------------------------------------------------------------------------
// prep_misc: fold W_first (per-stack half) through W0 -> Mn[2][9][4][128],
// fold biases (+gate bias, -log2e for f/r gates, sqrt2 for res), and build
// layer-1 column-bias table bias1n[2][384] (0 | -l2e*bf1 | -l2e*br1).
// grid(2), block(128)
// ---------------------------------------------------------------------------
__global__ void prep_misc(const float* __restrict__ Wf, const float* __restrict__ bfirst,
                          const float* __restrict__ aW0, const float* __restrict__ bW0,
                          const float* __restrict__ ab0, const float* __restrict__ bb0,
                          const float* __restrict__ ab1, const float* __restrict__ bb1,
                          float* __restrict__ Mn, float* __restrict__ biasn,
                          float* __restrict__ bias1n) {
    int s = blockIdx.x;
    int d = threadIdx.x;  // 0..127
    const float* W0s = s ? bW0 : aW0;
    const float* b0s = s ? bb0 : ab0;
    const float* b1s = s ? bb1 : ab1;
    for (int g = 0; g < 4; ++g) {
        float scale = (g == 1 || g == 2) ? -L2E : (g == 3 ? SQRT2 : 1.0f);
        float bias = 0.f;
        for (int i = 0; i < 64; ++i) bias += bfirst[s*64 + i] * W0s[i*512 + g*128 + d];
        for (int c = 0; c < NCH; ++c) {
            float acc = 0.f;
            for (int i = 0; i < 64; ++i)
                acc += Wf[(s*64 + i)*NCH + c] * W0s[i*512 + g*128 + d];
            Mn[((s*NCH + c)*4 + g)*128 + d] = scale * acc;
        }
        float bb = bias;
        if (g == 1) bb = bias + b0s[d];        // f-gate bias
        if (g == 2) bb = bias + b0s[128 + d];  // r-gate bias
        biasn[(s*4 + g)*128 + d] = scale * bb;
    }
    bias1n[s*384 + d      ] = 0.0f;
    bias1n[s*384 + 128 + d] = -L2E * b1s[d];
    bias1n[s*384 + 256 + d] = -L2E * b1s[128 + d];
}

// ---------------------------------------------------------------------------
// prep_bpack: pack W1 (128x384 fp32) into MFMA B-fragment order, bf16, with
// the -log2e gate scale folded into columns 128..383.
// Bpack[s][nt(24)][kt(4)][lane(64)][jj(8)];
// frag: lane holds B[k=kt*32+(lane>>4)*8+jj][n=nt*16+(lane&15)]
// grid(24,2), block(256)
// ---------------------------------------------------------------------------
__global__ void prep_bpack(const float* __restrict__ aW1, const float* __restrict__ bW1,
                           __hip_bfloat16* __restrict__ Bpack) {
    int nt = blockIdx.x, s = blockIdx.y;
    int kt = threadIdx.x >> 6, lane = threadIdx.x & 63;
    const float* W1s = s ? bW1 : aW1;
    int n = nt*16 + (lane & 15);
    float csc = (n < 128) ? 1.0f : -L2E;
    for (int jj = 0; jj < 8; ++jj) {
        int k = kt*32 + (lane >> 4)*8 + jj;
        Bpack[((size_t)((s*24 + nt)*4 + kt)*64 + lane)*8 + jj] =
            __float2bfloat16(csc * W1s[k*384 + n]);
    }
}

// ---------------------------------------------------------------------------
// scan0: fused input-conv (folded Mn) + layer-0 SRU scan.
// grid(KCH, 8), block(256): 4 waves = (stack, half).
// Writes h0[s][t][b][128] bf16 for t in [chunk*CL, (chunk+1)*CL).
// ---------------------------------------------------------------------------
__global__ __launch_bounds__(256) void scan0(const float* __restrict__ tensor,
        const float* __restrict__ av0, const float* __restrict__ bv0,
        const float* __restrict__ Mn, const float* __restrict__ biasn,
        __hip_bfloat16* __restrict__ h0) {
    __shared__ __align__(16) float ldsx[(CL + WU) * 12];
    int chunk = blockIdx.x, b = blockIdx.y;
    int tid = threadIdx.x, wid = tid >> 6, lane = tid & 63;
    int s = wid >> 1, half = wid & 1, d = half*64 + lane;

    int t0 = chunk*CL - WU; if (t0 < 0) t0 = 0;
    int tend = (chunk + 1)*CL;
    int nsteps = tend - t0;

    for (int c = 0; c < NCH; ++c) {
        const float* src = tensor + ((size_t)b*NCH + c)*T_LEN + t0;
        for (int j = tid; j < nsteps; j += 256) ldsx[j*12 + c] = src[j];
    }
    __syncthreads();

    f32x2 M01[NCH], M23[NCH], b01, b23;
    {
        float M[4][NCH], bi[4];
#pragma unroll
        for (int g = 0; g < 4; ++g) {
            bi[g] = biasn[(s*4 + g)*128 + d];
#pragma unroll
            for (int c = 0; c < NCH; ++c) M[g][c] = Mn[((s*NCH + c)*4 + g)*128 + d];
        }
#pragma unroll
        for (int c = 0; c < NCH; ++c) {
            M01[c] = (f32x2){M[0][c], M[1][c]};
            M23[c] = (f32x2){M[2][c], M[3][c]};
        }
        b01 = (f32x2){bi[0], bi[1]};
        b23 = (f32x2){bi[2], bi[3]};
    }
    const float* v0s = s ? bv0 : av0;
    float vf2 = -L2E * v0s[d];
    float vr2 = -L2E * v0s[128 + d];

    float cst = 0.f;
    int hw_start = chunk*CL;
    __hip_bfloat16* hbase = h0 + ((size_t)s*MROWS + b)*128 + d;

    for (int t = t0; t < tend; ++t) {
        int j = t - t0;
        const float4* xp = (const float4*)(ldsx + j*12);
        float4 xlo = xp[0], xhi = xp[1];
        float xv[NCH];
        xv[0]=xlo.x; xv[1]=xlo.y; xv[2]=xlo.z; xv[3]=xlo.w;
        xv[4]=xhi.x; xv[5]=xhi.y; xv[6]=xhi.z; xv[7]=xhi.w;
        xv[8]=ldsx[j*12 + 8];
        f32x2 u01 = b01, u23 = b23;
#pragma unroll
        for (int c = 0; c < NCH; ++c) {
            u01 += M01[c] * xv[c];
            u23 += M23[c] * xv[c];
        }
        float e  = __builtin_amdgcn_exp2f(fmaf(vf2, cst, u01.y));
        float cn = __builtin_amdgcn_rcpf(e + 1.0f) * fmaf(e, u01.x, cst);
        float er = __builtin_amdgcn_exp2f(fmaf(vr2, cn, u23.x));
        float rr = __builtin_amdgcn_rcpf(er + 1.0f);
        float h  = fmaf(rr, cn - u23.y, u23.y);   // u3 already sqrt2-scaled res
        cst = cn;
        if (t >= hw_start) hbase[(size_t)t * (BATCH*128)] = __float2bfloat16(h);
    }
}

// ---------------------------------------------------------------------------
// scan1f: fused layer-1 GEMM (MFMA, W1 in registers) + SRU scan + W_last proj.
// grid(KCH, 8), block(512) = 8 waves.
//   GEMM role: s_g = wid>>2, ntb = (wid&3)*6  -> 6 N-tiles x 4 K-frags each.
//   Scan role (wid<4): s_s = wid>>1, half = wid&1.
// Per 16-step tile: MFMA -> barrier -> store u (fp32, stride 388) -> barrier
// -> 16 serial SRU steps (waves 4-7 run ahead into next tile's MFMA).
// ---------------------------------------------------------------------------
__global__ __launch_bounds__(512) void scan1f(const __hip_bfloat16* __restrict__ h0,
        const __hip_bfloat16* __restrict__ Bpack, const float* __restrict__ bias1n,
        const float* __restrict__ av1, const float* __restrict__ bv1,
        const float* __restrict__ Wlast, float* __restrict__ pbuf) {
    __shared__ __align__(16) float ush[2*16*388];   // 49,664 B
    int chunk = blockIdx.x, b = blockIdx.y;
    int tid = threadIdx.x, wid = tid >> 6, lane = tid & 63;
    int s_g = wid >> 2, ntb = (wid & 3)*6, cl = lane & 15, rsel = lane >> 4;
    int tw = chunk*CL, t0 = tw - WUF;   // may be negative for chunk 0

    // W1 fragments in registers: 6 nt x 4 kt x 16B = 96 VGPRs, reused 71 tiles
    bf16x8 Bfr[6][4];
    const bf16x8* bsrc = (const bf16x8*)Bpack;
#pragma unroll
    for (int i = 0; i < 6; ++i)
#pragma unroll
        for (int kt = 0; kt < 4; ++kt)
            Bfr[i][kt] = bsrc[((s_g*24 + ntb + i)*4 + kt)*64 + lane];
    float bias[6];
#pragma unroll
    for (int i = 0; i < 6; ++i) bias[i] = bias1n[s_g*384 + (ntb + i)*16 + cl];

    // scan-role setup (valid deref only for wid<4)
    int s_s = wid >> 1, half = wid & 1, d = half*64 + lane;
    const float* v1s = (s_s & 1) ? bv1 : av1;
    float vf2 = -L2E * v1s[d], vr2 = -L2E * v1s[128 + d];
    float wl = Wlast[d];
    float cst = 0.f;
    float* pb = pbuf + ((size_t)(wid & 3)*BATCH + b)*T_LEN;
    const __hip_bfloat16* hres = h0 + ((size_t)(s_s & 1)*MROWS + b)*128 + d;

    const __hip_bfloat16* habase = h0 + ((size_t)s_g*MROWS + b)*128;

    for (int tile = 0; tile < NTIL; ++tile) {
        int tt0 = t0 + tile*16;
        // A-fragments: row = tt0+cl (clamped for t<0), 16B per lane per kt
        int trow = tt0 + cl; if (trow < 0) trow = 0;
        const __hip_bfloat16* ap = habase + (size_t)trow*(BATCH*128) + rsel*8;
        bf16x8 Afr[4];
#pragma unroll
        for (int kt = 0; kt < 4; ++kt) Afr[kt] = *(const bf16x8*)(ap + kt*32);

        f32x4 acc[6];
#pragma unroll
        for (int i = 0; i < 6; ++i) acc[i] = (f32x4){bias[i], bias[i], bias[i], bias[i]};
#pragma unroll
        for (int kt = 0; kt < 4; ++kt)
#pragma unroll
            for (int i = 0; i < 6; ++i)
                acc[i] = __builtin_amdgcn_mfma_f32_16x16x32_bf16(Afr[kt], Bfr[i][kt], acc[i], 0, 0, 0);

        __syncthreads();   // previous tile's scan has finished reading ush
#pragma unroll
        for (int i = 0; i < 6; ++i) {
            int col = (ntb + i)*16 + cl;
#pragma unroll
            for (int j = 0; j < 4; ++j)
                ush[(s_g*16 + rsel*4 + j)*388 + col] = acc[i][j];
        }
        __syncthreads();   // u-tile ready

        if (wid < 4) {
            for (int tt = 0; tt < 16; ++tt) {
                int t = tt0 + tt;
                if (t < 0) continue;
                const float* ur = ush + (s_s*16 + tt)*388;
                float u0 = ur[d], u1 = ur[128 + d], u2 = ur[256 + d];
                float res = __bfloat162float(hres[(size_t)t*(BATCH*128)]);
                float e  = __builtin_amdgcn_exp2f(fmaf(vf2, cst, u1));
                float cn = __builtin_amdgcn_rcpf(e + 1.0f) * fmaf(e, u0, cst);
                float er = __builtin_amdgcn_exp2f(fmaf(vr2, cn, u2));
                float rr = __builtin_amdgcn_rcpf(er + 1.0f);
                float sres = SQRT2 * res;
                float h  = fmaf(rr, cn - sres, sres);
                cst = cn;
                if (t >= tw) {
                    float p = wl * h;
#pragma unroll
                    for (int m = 32; m >= 1; m >>= 1) p += __shfl_xor(p, m);
                    if (lane == 0) pb[t] = p;
                }
            }
        }
    }
}

// ---------------------------------------------------------------------------
// finalk: out[b][t] = b_last + sum over 4 partial slots
// ---------------------------------------------------------------------------
__global__ void finalk(const float* __restrict__ pbuf, const float* __restrict__ blast,
                       float* __restrict__ out) {
    int idx = blockIdx.x*256 + threadIdx.x;
    if (idx >= BATCH*T_LEN) return;
    int b = idx / T_LEN, t = idx - b*T_LEN;
    float v = blast[0];
#pragma unroll
    for (int k = 0; k < 4; ++k) v += pbuf[((size_t)k*BATCH + b)*T_LEN + t];
    out[idx] = v;
}

// ---------------------------------------------------------------------------
extern "C" void kernel_launch(void* const* d_in, const int* in_sizes, int n_in,
                              void* d_out, int out_size, void* d_ws, size_t ws_size,
                              hipStream_t stream) {
    const float* tensor = (const float*)d_in[0];
    const float* Wfirst = (const float*)d_in[1];
    const float* bfirst = (const float*)d_in[2];
    const float* Wlast  = (const float*)d_in[3];
    const float* blast  = (const float*)d_in[4];
    const float* aW0 = (const float*)d_in[5];
    const float* av0 = (const float*)d_in[6];
    const float* ab0 = (const float*)d_in[7];
    const float* aW1 = (const float*)d_in[8];
    const float* av1 = (const float*)d_in[9];
    const float* ab1 = (const float*)d_in[10];
    const float* bW0 = (const float*)d_in[11];
    const float* bv0 = (const float*)d_in[12];
    const float* bb0 = (const float*)d_in[13];
    const float* bW1 = (const float*)d_in[14];
    const float* bv1 = (const float*)d_in[15];
    const float* bb1 = (const float*)d_in[16];
    float* out = (float*)d_out;

    char* ws = (char*)d_ws;
    size_t off = 0;
    float* Mn     = (float*)(ws + off); off += 2*9*4*128*sizeof(float);
    float* biasn  = (float*)(ws + off); off += 2*4*128*sizeof(float);
    float* bias1n = (float*)(ws + off); off += 2*384*sizeof(float);
    off = (off + 255) & ~(size_t)255;
    __hip_bfloat16* Bpack = (__hip_bfloat16*)(ws + off); off += (size_t)2*24*4*64*8*2;
    off = (off + 255) & ~(size_t)255;
    float* pbuf = (float*)(ws + off); off += (size_t)4*BATCH*T_LEN*sizeof(float);
    off = (off + 255) & ~(size_t)255;
    __hip_bfloat16* h0 = (__hip_bfloat16*)(ws + off); off += (size_t)2*MROWS*128*2;
    (void)ws_size; (void)in_sizes; (void)n_in; (void)out_size;
    // total workspace: ~135.4 MB

    prep_misc<<<dim3(2), 128, 0, stream>>>(Wfirst, bfirst, aW0, bW0, ab0, bb0, ab1, bb1,
                                           Mn, biasn, bias1n);
    prep_bpack<<<dim3(24, 2), 256, 0, stream>>>(aW1, bW1, Bpack);
    scan0<<<dim3(KCH, BATCH), 256, 0, stream>>>(tensor, av0, bv0, Mn, biasn, h0);
    scan1f<<<dim3(KCH, BATCH), 512, 0, stream>>>(h0, Bpack, bias1n, av1, bv1, Wlast, pbuf);
    finalk<<<dim3((BATCH*T_LEN + 255)/256), 256, 0, stream>>>(pbuf, blast, out);
}

// Round 4
// 480.570 us; speedup vs baseline: 1.7528x; 1.7528x over previous
//
#include <hip/hip_runtime.h>
#include <hip/hip_bf16.h>

#define L2E   1.44269504088896340736f
#define SQRT2 1.41421356237309504880f

#define T_LEN 32000
#define BATCH 8
#define NCH   9

// scan0 chunking
#define KCH0  64
#define CL0   500
#define WU    128      // layer-0 warm-up
// scan1f chunking
#define KCH1  32
#define CL1   1000
#define WUF   136      // layer-1 warm-up; (CL1+WUF)=1136=71*16
#define NTIL  71

#define MROWS (T_LEN*BATCH)   // 256000 rows per stack

typedef __bf16 bf16x8 __attribute__((ext_vector_type(8)));
typedef float  f32x4  __attribute__((ext_vector_type(4)));
typedef float  f32x2  __attribute__((ext_vector_type(2)));

// ---------------------------------------------------------------------------
// prep_misc: fold W_first (per-stack half) through W0 -> Mn[2][9][4][128],
// fold biases (+gate bias, -log2e for f/r gates, sqrt2 for res), and build
// layer-1 column-bias table bias1n[2][384]. grid(2,4): s = x, gate = y.
// ---------------------------------------------------------------------------
__global__ void prep_misc(const float* __restrict__ Wf, const float* __restrict__ bfirst,
                          const float* __restrict__ aW0, const float* __restrict__ bW0,
                          const float* __restrict__ ab0, const float* __restrict__ bb0,
                          const float* __restrict__ ab1, const float* __restrict__ bb1,
                          float* __restrict__ Mn, float* __restrict__ biasn,
                          float* __restrict__ bias1n) {
    int s = blockIdx.x, g = blockIdx.y;
    int d = threadIdx.x;  // 0..127
    const float* W0s = s ? bW0 : aW0;
    const float* b0s = s ? bb0 : ab0;
    const float* b1s = s ? bb1 : ab1;

    float scale = (g == 1 || g == 2) ? -L2E : (g == 3 ? SQRT2 : 1.0f);
    float bias = 0.f;
    for (int i = 0; i < 64; ++i) bias += bfirst[s*64 + i] * W0s[i*512 + g*128 + d];
    for (int c = 0; c < NCH; ++c) {
        float acc = 0.f;
        for (int i = 0; i < 64; ++i)
            acc += Wf[(s*64 + i)*NCH + c] * W0s[i*512 + g*128 + d];
        Mn[((s*NCH + c)*4 + g)*128 + d] = scale * acc;
    }
    float bb = bias;
    if (g == 1) bb = bias + b0s[d];        // f-gate bias
    if (g == 2) bb = bias + b0s[128 + d];  // r-gate bias
    biasn[(s*4 + g)*128 + d] = scale * bb;

    if (g == 0) {
        bias1n[s*384 + d      ] = 0.0f;
        bias1n[s*384 + 128 + d] = -L2E * b1s[d];
        bias1n[s*384 + 256 + d] = -L2E * b1s[128 + d];
    }
}

// ---------------------------------------------------------------------------
// prep_bpack: pack W1 (128x384 fp32) into MFMA B-fragment order, bf16, with
// -log2e folded into columns 128..383.
// Bpack[s][nt(24)][kt(4)][lane(64)][jj(8)];
// frag: lane holds B[k=kt*32+(lane>>4)*8+jj][n=nt*16+(lane&15)]
// grid(24,2), block(256)
// ---------------------------------------------------------------------------
__global__ void prep_bpack(const float* __restrict__ aW1, const float* __restrict__ bW1,
                           __hip_bfloat16* __restrict__ Bpack) {
    int nt = blockIdx.x, s = blockIdx.y;
    int kt = threadIdx.x >> 6, lane = threadIdx.x & 63;
    const float* W1s = s ? bW1 : aW1;
    int n = nt*16 + (lane & 15);
    float csc = (n < 128) ? 1.0f : -L2E;
    for (int jj = 0; jj < 8; ++jj) {
        int k = kt*32 + (lane >> 4)*8 + jj;
        Bpack[((size_t)((s*24 + nt)*4 + kt)*64 + lane)*8 + jj] =
            __float2bfloat16(csc * W1s[k*384 + n]);
    }
}

// ---------------------------------------------------------------------------
// scan0: fused input-conv (folded Mn) + layer-0 SRU scan.
// grid(KCH0, 8), block(256): 4 waves = (stack, half).
// 4-step groups, 2-buffer pipeline: u-dots of group g+1 (independent VALU)
// interleave with the serial chain of group g. 2 blocks/CU.
// ---------------------------------------------------------------------------
__global__ __launch_bounds__(256) void scan0(const float* __restrict__ tensor,
        const float* __restrict__ av0, const float* __restrict__ bv0,
        const float* __restrict__ Mn, const float* __restrict__ biasn,
        __hip_bfloat16* __restrict__ h0) {
    __shared__ __align__(16) float ldsx[(CL0 + WU) * 12];
    int chunk = blockIdx.x, b = blockIdx.y;
    int tid = threadIdx.x, wid = tid >> 6, lane = tid & 63;
    int s = wid >> 1, half = wid & 1, d = half*64 + lane;

    int t0 = chunk*CL0 - WU; if (t0 < 0) t0 = 0;
    int tend = (chunk + 1)*CL0;
    int nsteps = tend - t0;          // 500 or 628, both /4

    for (int c = 0; c < NCH; ++c) {
        const float* src = tensor + ((size_t)b*NCH + c)*T_LEN + t0;
        for (int j = tid; j < nsteps; j += 256) ldsx[j*12 + c] = src[j];
    }
    __syncthreads();

    f32x2 M01[NCH], M23[NCH], b01, b23;
    {
        float M[4][NCH], bi[4];
#pragma unroll
        for (int g = 0; g < 4; ++g) {
            bi[g] = biasn[(s*4 + g)*128 + d];
#pragma unroll
            for (int c = 0; c < NCH; ++c) M[g][c] = Mn[((s*NCH + c)*4 + g)*128 + d];
        }
#pragma unroll
        for (int c = 0; c < NCH; ++c) {
            M01[c] = (f32x2){M[0][c], M[1][c]};
            M23[c] = (f32x2){M[2][c], M[3][c]};
        }
        b01 = (f32x2){bi[0], bi[1]};
        b23 = (f32x2){bi[2], bi[3]};
    }
    const float* v0s = s ? bv0 : av0;
    float vf2 = -L2E * v0s[d];
    float vr2 = -L2E * v0s[128 + d];

    float cst = 0.f;
    int hw_off = chunk*CL0 - t0;     // first step index to store (0 or WU)
    __hip_bfloat16* hbase = h0 + ((size_t)s*MROWS + b)*128 + d;

    auto compU = [&](int grp, f32x2* u01v, f32x2* u23v) {
#pragma unroll
        for (int k = 0; k < 4; ++k) {
            const float* xr = ldsx + (grp*4 + k)*12;
            float4 xlo = *(const float4*)xr;
            float4 xhi = *(const float4*)(xr + 4);
            float x8 = xr[8];
            f32x2 a = b01, c2 = b23;
            a += M01[0]*xlo.x; c2 += M23[0]*xlo.x;
            a += M01[1]*xlo.y; c2 += M23[1]*xlo.y;
            a += M01[2]*xlo.z; c2 += M23[2]*xlo.z;
            a += M01[3]*xlo.w; c2 += M23[3]*xlo.w;
            a += M01[4]*xhi.x; c2 += M23[4]*xhi.x;
            a += M01[5]*xhi.y; c2 += M23[5]*xhi.y;
            a += M01[6]*xhi.z; c2 += M23[6]*xhi.z;
            a += M01[7]*xhi.w; c2 += M23[7]*xhi.w;
            a += M01[8]*x8;    c2 += M23[8]*x8;
            u01v[k] = a; u23v[k] = c2;
        }
    };
    auto chain = [&](f32x2* u01v, f32x2* u23v, int grp) {
#pragma unroll
        for (int k = 0; k < 4; ++k) {
            float e  = __builtin_amdgcn_exp2f(fmaf(vf2, cst, u01v[k].y));
            float cn = __builtin_amdgcn_rcpf(e + 1.0f) * fmaf(e, u01v[k].x, cst);
            float er = __builtin_amdgcn_exp2f(fmaf(vr2, cn, u23v[k].x));
            float rr = __builtin_amdgcn_rcpf(er + 1.0f);
            float h  = fmaf(rr, cn - u23v[k].y, u23v[k].y);
            cst = cn;
            int j = grp*4 + k;
            if (j >= hw_off) hbase[(size_t)(t0 + j)*(BATCH*128)] = __float2bfloat16(h);
        }
    };

    f32x2 uA01[4], uA23[4], uB01[4], uB23[4];
    int ngrp = nsteps >> 2;
    compU(0, uA01, uA23);
    int g = 0;
    while (g + 2 <= ngrp) {
        compU(g + 1, uB01, uB23);
        chain(uA01, uA23, g);
        if (g + 2 < ngrp) compU(g + 2, uA01, uA23);
        chain(uB01, uB23, g + 1);
        g += 2;
    }
    if (g < ngrp) chain(uA01, uA23, g);
}

// ---------------------------------------------------------------------------
// scan1f: fused layer-1 GEMM (MFMA, W1 in registers) + SRU scan + W_last proj.
// grid(KCH1, 8), block(512) = 8 waves.
//   GEMM role: s_g = wid>>2, ntb = (wid&3)*6  -> 6 N-tiles x 4 K-frags.
//   Scan role (wid<4): s_s = wid>>1, half = wid&1.
// Software pipeline: A-frags + residuals for tile t+1 prefetched during the
// store phase of tile t; scan phase runs on register-preloaded u/res; the
// W_last shuffle-reduce is hoisted OUT of the serial chain.
// ---------------------------------------------------------------------------
__global__ __launch_bounds__(512) void scan1f(const __hip_bfloat16* __restrict__ h0,
        const __hip_bfloat16* __restrict__ Bpack, const float* __restrict__ bias1n,
        const float* __restrict__ av1, const float* __restrict__ bv1,
        const float* __restrict__ Wlast, float* __restrict__ pbuf) {
    __shared__ __align__(16) float ush[2*16*388];   // 49,664 B
    int chunk = blockIdx.x, b = blockIdx.y;
    int tid = threadIdx.x, wid = tid >> 6, lane = tid & 63;
    int s_g = wid >> 2, ntb = (wid & 3)*6, cl = lane & 15, rsel = lane >> 4;
    int tw = chunk*CL1, t0 = tw - WUF;   // negative for chunk 0

    // W1 fragments in registers: 6 nt x 4 kt x 16B = 96 VGPRs, reused 71 tiles
    bf16x8 Bfr[6][4];
    const bf16x8* bsrc = (const bf16x8*)Bpack;
#pragma unroll
    for (int i = 0; i < 6; ++i)
#pragma unroll
        for (int kt = 0; kt < 4; ++kt)
            Bfr[i][kt] = bsrc[((s_g*24 + ntb + i)*4 + kt)*64 + lane];
    float bias[6];
#pragma unroll
    for (int i = 0; i < 6; ++i) bias[i] = bias1n[s_g*384 + (ntb + i)*16 + cl];

    // scan-role setup (waves 0-3)
    int s_s = wid >> 1, half = wid & 1, d = half*64 + lane;
    const float* v1s = (s_s & 1) ? bv1 : av1;
    float vf2 = -L2E * v1s[d], vr2 = -L2E * v1s[128 + d];
    float wl = Wlast[d];
    float cst = 0.f;
    float* pb = pbuf + ((size_t)(wid & 3)*BATCH + b)*T_LEN;
    const __hip_bfloat16* hres = h0 + ((size_t)(s_s & 1)*MROWS + b)*128 + d;
    const __hip_bfloat16* habase = h0 + ((size_t)s_g*MROWS + b)*128;

    auto loadA = [&](int tile, bf16x8* A) {
        int trow = t0 + tile*16 + cl; if (trow < 0) trow = 0;
        const __hip_bfloat16* ap = habase + (size_t)trow*(BATCH*128) + rsel*8;
#pragma unroll
        for (int kt = 0; kt < 4; ++kt) A[kt] = *(const bf16x8*)(ap + kt*32);
    };
    auto loadR = [&](int tile, float* rv) {
#pragma unroll
        for (int k = 0; k < 16; ++k) {
            int t = t0 + tile*16 + k; if (t < 0) t = 0;
            rv[k] = __bfloat162float(hres[(size_t)t*(BATCH*128)]);
        }
    };

    bf16x8 Afr[4], Afrn[4];
    float resv[16], resn[16];
    loadA(0, Afr);
    if (wid < 4) loadR(0, resv);

    for (int tile = 0; tile < NTIL; ++tile) {
        int tt0 = t0 + tile*16;

        f32x4 acc[6];
#pragma unroll
        for (int i = 0; i < 6; ++i) acc[i] = (f32x4){bias[i], bias[i], bias[i], bias[i]};
#pragma unroll
        for (int kt = 0; kt < 4; ++kt)
#pragma unroll
            for (int i = 0; i < 6; ++i)
                acc[i] = __builtin_amdgcn_mfma_f32_16x16x32_bf16(Afr[kt], Bfr[i][kt], acc[i], 0, 0, 0);

        __syncthreads();   // previous tile's scan has finished reading ush
#pragma unroll
        for (int i = 0; i < 6; ++i) {
            int col = (ntb + i)*16 + cl;
#pragma unroll
            for (int j = 0; j < 4; ++j)
                ush[(s_g*16 + rsel*4 + j)*388 + col] = acc[i][j];
        }

        // prefetch next tile's A-frags and residuals (latency hides under scan)
        int tnext = (tile + 1 < NTIL) ? tile + 1 : tile;
        loadA(tnext, Afrn);
        if (wid < 4) loadR(tnext, resn);

        __syncthreads();   // u-tile ready

        if (wid < 4) {
#pragma unroll
            for (int sub = 0; sub < 2; ++sub) {
                float u0v[8], u1v[8], u2v[8], hv[8];
#pragma unroll
                for (int k = 0; k < 8; ++k) {
                    const float* ur = ush + (s_s*16 + sub*8 + k)*388;
                    u0v[k] = ur[d]; u1v[k] = ur[128 + d]; u2v[k] = ur[256 + d];
                }
#pragma unroll
                for (int k = 0; k < 8; ++k) {
                    int t = tt0 + sub*8 + k;
                    float e  = __builtin_amdgcn_exp2f(fmaf(vf2, cst, u1v[k]));
                    float cn = __builtin_amdgcn_rcpf(e + 1.0f) * fmaf(e, u0v[k], cst);
                    float er = __builtin_amdgcn_exp2f(fmaf(vr2, cn, u2v[k]));
                    float rr = __builtin_amdgcn_rcpf(er + 1.0f);
                    float sr = SQRT2 * resv[sub*8 + k];
                    hv[k] = fmaf(rr, cn - sr, sr);
                    cst = (t >= 0) ? cn : cst;   // chunk-0 left pad
                }
                // reduction hoisted out of the serial chain
                float sel = 0.f;
#pragma unroll
                for (int k = 0; k < 8; ++k) {
                    float p = wl * hv[k];
#pragma unroll
                    for (int m = 32; m >= 1; m >>= 1) p += __shfl_xor(p, m);
                    if (lane == k) sel = p;
                }
                int tsel = tt0 + sub*8 + lane;
                if (lane < 8 && tsel >= tw) pb[tsel] = sel;
            }
        }
#pragma unroll
        for (int kt = 0; kt < 4; ++kt) Afr[kt] = Afrn[kt];
        if (wid < 4) {
#pragma unroll
            for (int k = 0; k < 16; ++k) resv[k] = resn[k];
        }
    }
}

// ---------------------------------------------------------------------------
// finalk: out[b][t] = b_last + sum over 4 partial slots
// ---------------------------------------------------------------------------
__global__ void finalk(const float* __restrict__ pbuf, const float* __restrict__ blast,
                       float* __restrict__ out) {
    int idx = blockIdx.x*256 + threadIdx.x;
    if (idx >= BATCH*T_LEN) return;
    int b = idx / T_LEN, t = idx - b*T_LEN;
    float v = blast[0];
#pragma unroll
    for (int k = 0; k < 4; ++k) v += pbuf[((size_t)k*BATCH + b)*T_LEN + t];
    out[idx] = v;
}

// ---------------------------------------------------------------------------
extern "C" void kernel_launch(void* const* d_in, const int* in_sizes, int n_in,
                              void* d_out, int out_size, void* d_ws, size_t ws_size,
                              hipStream_t stream) {
    const float* tensor = (const float*)d_in[0];
    const float* Wfirst = (const float*)d_in[1];
    const float* bfirst = (const float*)d_in[2];
    const float* Wlast  = (const float*)d_in[3];
    const float* blast  = (const float*)d_in[4];
    const float* aW0 = (const float*)d_in[5];
    const float* av0 = (const float*)d_in[6];
    const float* ab0 = (const float*)d_in[7];
    const float* aW1 = (const float*)d_in[8];
    const float* av1 = (const float*)d_in[9];
    const float* ab1 = (const float*)d_in[10];
    const float* bW0 = (const float*)d_in[11];
    const float* bv0 = (const float*)d_in[12];
    const float* bb0 = (const float*)d_in[13];
    const float* bW1 = (const float*)d_in[14];
    const float* bv1 = (const float*)d_in[15];
    const float* bb1 = (const float*)d_in[16];
    float* out = (float*)d_out;

    char* ws = (char*)d_ws;
    size_t off = 0;
    float* Mn     = (float*)(ws + off); off += 2*9*4*128*sizeof(float);
    float* biasn  = (float*)(ws + off); off += 2*4*128*sizeof(float);
    float* bias1n = (float*)(ws + off); off += 2*384*sizeof(float);
    off = (off + 255) & ~(size_t)255;
    __hip_bfloat16* Bpack = (__hip_bfloat16*)(ws + off); off += (size_t)2*24*4*64*8*2;
    off = (off + 255) & ~(size_t)255;
    float* pbuf = (float*)(ws + off); off += (size_t)4*BATCH*T_LEN*sizeof(float);
    off = (off + 255) & ~(size_t)255;
    __hip_bfloat16* h0 = (__hip_bfloat16*)(ws + off); off += (size_t)2*MROWS*128*2;
    (void)ws_size; (void)in_sizes; (void)n_in; (void)out_size;
    // total workspace: ~135.4 MB

    prep_misc<<<dim3(2, 4), 128, 0, stream>>>(Wfirst, bfirst, aW0, bW0, ab0, bb0, ab1, bb1,
                                              Mn, biasn, bias1n);
    prep_bpack<<<dim3(24, 2), 256, 0, stream>>>(aW1, bW1, Bpack);
    scan0<<<dim3(KCH0, BATCH), 256, 0, stream>>>(tensor, av0, bv0, Mn, biasn, h0);
    scan1f<<<dim3(KCH1, BATCH), 512, 0, stream>>>(h0, Bpack, bias1n, av1, bv1, Wlast, pbuf);
    finalk<<<dim3((BATCH*T_LEN + 255)/256), 256, 0, stream>>>(pbuf, blast, out);
}

// Round 5
// 457.337 us; speedup vs baseline: 1.8419x; 1.0508x over previous
//
#include <hip/hip_runtime.h>
#include <hip/hip_bf16.h>

#define L2E   1.44269504088896340736f
#define SQRT2 1.41421356237309504880f

#define T_LEN 32000
#define BATCH 8
#define NCH   9

// scan0 chunking
#define KCH0  125
#define CL0   256
#define WU    128      // layer-0 warm-up (nsteps 384 or 256, both /4)
// scan1f chunking
#define KCH1  32
#define CL1   1000
#define WUF   136      // layer-1 warm-up; (CL1+WUF)=1136=71*16
#define NTIL  71

#define MROWS (T_LEN*BATCH)   // 256000 rows per stack

typedef __bf16 bf16x8 __attribute__((ext_vector_type(8)));
typedef float  f32x4  __attribute__((ext_vector_type(4)));
typedef float  f32x2  __attribute__((ext_vector_type(2)));

// ---------------------------------------------------------------------------
// prep_misc: fold W_first (per-stack half) through W0 -> Mn[2][9][4][128],
// fold biases (+gate bias, -log2e for f/r gates, sqrt2 for res), and build
// layer-1 column-bias table bias1n[2][384]. grid(2,4): s = x, gate = y.
// ---------------------------------------------------------------------------
__global__ void prep_misc(const float* __restrict__ Wf, const float* __restrict__ bfirst,
                          const float* __restrict__ aW0, const float* __restrict__ bW0,
                          const float* __restrict__ ab0, const float* __restrict__ bb0,
                          const float* __restrict__ ab1, const float* __restrict__ bb1,
                          float* __restrict__ Mn, float* __restrict__ biasn,
                          float* __restrict__ bias1n) {
    int s = blockIdx.x, g = blockIdx.y;
    int d = threadIdx.x;  // 0..127
    const float* W0s = s ? bW0 : aW0;
    const float* b0s = s ? bb0 : ab0;
    const float* b1s = s ? bb1 : ab1;

    float scale = (g == 1 || g == 2) ? -L2E : (g == 3 ? SQRT2 : 1.0f);
    float bias = 0.f;
    for (int i = 0; i < 64; ++i) bias += bfirst[s*64 + i] * W0s[i*512 + g*128 + d];
    for (int c = 0; c < NCH; ++c) {
        float acc = 0.f;
        for (int i = 0; i < 64; ++i)
            acc += Wf[(s*64 + i)*NCH + c] * W0s[i*512 + g*128 + d];
        Mn[((s*NCH + c)*4 + g)*128 + d] = scale * acc;
    }
    float bb = bias;
    if (g == 1) bb = bias + b0s[d];        // f-gate bias
    if (g == 2) bb = bias + b0s[128 + d];  // r-gate bias
    biasn[(s*4 + g)*128 + d] = scale * bb;

    if (g == 0) {
        bias1n[s*384 + d      ] = 0.0f;
        bias1n[s*384 + 128 + d] = -L2E * b1s[d];
        bias1n[s*384 + 256 + d] = -L2E * b1s[128 + d];
    }
}

// ---------------------------------------------------------------------------
// prep_bpack: pack W1 (128x384 fp32) into MFMA B-fragment order, bf16, with
// -log2e folded into columns 128..383.
// Bpack[s][nt(24)][kt(4)][lane(64)][jj(8)];
// frag: lane holds B[k=kt*32+(lane>>4)*8+jj][n=nt*16+(lane&15)]
// grid(24,2), block(256)
// ---------------------------------------------------------------------------
__global__ void prep_bpack(const float* __restrict__ aW1, const float* __restrict__ bW1,
                           __hip_bfloat16* __restrict__ Bpack) {
    int nt = blockIdx.x, s = blockIdx.y;
    int kt = threadIdx.x >> 6, lane = threadIdx.x & 63;
    const float* W1s = s ? bW1 : aW1;
    int n = nt*16 + (lane & 15);
    float csc = (n < 128) ? 1.0f : -L2E;
    for (int jj = 0; jj < 8; ++jj) {
        int k = kt*32 + (lane >> 4)*8 + jj;
        Bpack[((size_t)((s*24 + nt)*4 + kt)*64 + lane)*8 + jj] =
            __float2bfloat16(csc * W1s[k*384 + n]);
    }
}

// ---------------------------------------------------------------------------
// scan0: fused input-conv (folded Mn) + layer-0 SRU scan.
// grid(KCH0, 8), block(256): 4 waves = (stack, half). 4 blocks/CU so each
// SIMD interleaves 4 independent chains.
// ---------------------------------------------------------------------------
__global__ __launch_bounds__(256, 4) void scan0(const float* __restrict__ tensor,
        const float* __restrict__ av0, const float* __restrict__ bv0,
        const float* __restrict__ Mn, const float* __restrict__ biasn,
        __hip_bfloat16* __restrict__ h0) {
    __shared__ __align__(16) float ldsx[(CL0 + WU) * 12];
    int chunk = blockIdx.x, b = blockIdx.y;
    int tid = threadIdx.x, wid = tid >> 6, lane = tid & 63;
    int s = wid >> 1, half = wid & 1, d = half*64 + lane;

    int t0 = chunk*CL0 - WU; if (t0 < 0) t0 = 0;
    int tend = (chunk + 1)*CL0;
    int nsteps = tend - t0;          // 384 or 256, both /4, ngrp even

    for (int c = 0; c < NCH; ++c) {
        const float* src = tensor + ((size_t)b*NCH + c)*T_LEN + t0;
        for (int j = tid; j < nsteps; j += 256) ldsx[j*12 + c] = src[j];
    }
    __syncthreads();

    f32x2 M01[NCH], M23[NCH], b01, b23;
    {
        float M[4][NCH], bi[4];
#pragma unroll
        for (int g = 0; g < 4; ++g) {
            bi[g] = biasn[(s*4 + g)*128 + d];
#pragma unroll
            for (int c = 0; c < NCH; ++c) M[g][c] = Mn[((s*NCH + c)*4 + g)*128 + d];
        }
#pragma unroll
        for (int c = 0; c < NCH; ++c) {
            M01[c] = (f32x2){M[0][c], M[1][c]};
            M23[c] = (f32x2){M[2][c], M[3][c]};
        }
        b01 = (f32x2){bi[0], bi[1]};
        b23 = (f32x2){bi[2], bi[3]};
    }
    const float* v0s = s ? bv0 : av0;
    float vf2 = -L2E * v0s[d];
    float vr2 = -L2E * v0s[128 + d];

    float cst = 0.f;
    int hw_off = chunk*CL0 - t0;     // first step index to store (0 or WU)
    __hip_bfloat16* hbase = h0 + ((size_t)s*MROWS + b)*128 + d;

    auto compU = [&](int grp, f32x2* u01v, f32x2* u23v) {
#pragma unroll
        for (int k = 0; k < 4; ++k) {
            const float* xr = ldsx + (grp*4 + k)*12;
            float4 xlo = *(const float4*)xr;
            float4 xhi = *(const float4*)(xr + 4);
            float x8 = xr[8];
            f32x2 a = b01, c2 = b23;
            a += M01[0]*xlo.x; c2 += M23[0]*xlo.x;
            a += M01[1]*xlo.y; c2 += M23[1]*xlo.y;
            a += M01[2]*xlo.z; c2 += M23[2]*xlo.z;
            a += M01[3]*xlo.w; c2 += M23[3]*xlo.w;
            a += M01[4]*xhi.x; c2 += M23[4]*xhi.x;
            a += M01[5]*xhi.y; c2 += M23[5]*xhi.y;
            a += M01[6]*xhi.z; c2 += M23[6]*xhi.z;
            a += M01[7]*xhi.w; c2 += M23[7]*xhi.w;
            a += M01[8]*x8;    c2 += M23[8]*x8;
            u01v[k] = a; u23v[k] = c2;
        }
    };
    auto chain = [&](f32x2* u01v, f32x2* u23v, int grp) {
#pragma unroll
        for (int k = 0; k < 4; ++k) {
            float e  = __builtin_amdgcn_exp2f(fmaf(vf2, cst, u01v[k].y));
            float g  = __builtin_amdgcn_rcpf(e + 1.0f);
            float cn = fmaf(g, cst - u01v[k].x, u01v[k].x);
            float er = __builtin_amdgcn_exp2f(fmaf(vr2, cn, u23v[k].x));
            float rr = __builtin_amdgcn_rcpf(er + 1.0f);
            float h  = fmaf(rr, cn - u23v[k].y, u23v[k].y);
            cst = cn;
            int j = grp*4 + k;
            if (j >= hw_off) hbase[(size_t)(t0 + j)*(BATCH*128)] = __float2bfloat16(h);
        }
    };

    f32x2 uA01[4], uA23[4], uB01[4], uB23[4];
    int ngrp = nsteps >> 2;
    compU(0, uA01, uA23);
    int g = 0;
    while (g + 2 <= ngrp) {
        compU(g + 1, uB01, uB23);
        chain(uA01, uA23, g);
        if (g + 2 < ngrp) compU(g + 2, uA01, uA23);
        chain(uB01, uB23, g + 1);
        g += 2;
    }
}

// ---------------------------------------------------------------------------
// scan1f: fused layer-1 GEMM + SRU scan + W_last proj, producer/consumer.
// grid(KCH1, 8), block(768) = 12 waves:
//   waves 0-3 : scan-only (stack = wid>>1, half = wid&1)
//   waves 4-11: GEMM-only (gw = wid-4; s_g = gw>>2; 6 N-tiles, W1 in regs)
// One barrier per tile; ping-pong ush/hstg: GEMM writes u(t+1),h(t+1) -> pp^1
// while scan consumes tile t from pp. A-loads issued a full tile ahead.
// ---------------------------------------------------------------------------
__global__ __launch_bounds__(768, 3) void scan1f(const __hip_bfloat16* __restrict__ h0,
        const __hip_bfloat16* __restrict__ Bpack, const float* __restrict__ bias1n,
        const float* __restrict__ av1, const float* __restrict__ bv1,
        const float* __restrict__ Wlast, float* __restrict__ pbuf) {
    __shared__ __align__(16) float ush[2][2][16][388];       // 99,328 B
    __shared__ unsigned int hstg[2][2][16][64];              // 16,384 B
    int chunk = blockIdx.x, b = blockIdx.y;
    int tid = threadIdx.x, wid = tid >> 6, lane = tid & 63;
    int cl = lane & 15, rsel = lane >> 4;
    int tw = chunk*CL1, t0 = tw - WUF;   // negative for chunk 0
    int pp = 0;

    if (wid >= 4) {
        // ================= GEMM role =================
        int gw = wid - 4;
        int s_g = gw >> 2;            // 0..1
        int ntb = (gw & 3) * 6;       // 0,6,12,18
        bool hwr = ((gw & 3) == 0);   // wid 4 -> stack0, wid 8 -> stack1
        bf16x8 Bfr[6][4];
        const bf16x8* bsrc = (const bf16x8*)Bpack;
#pragma unroll
        for (int i = 0; i < 6; ++i)
#pragma unroll
            for (int kt = 0; kt < 4; ++kt)
                Bfr[i][kt] = bsrc[((s_g*24 + ntb + i)*4 + kt)*64 + lane];
        float bias[6];
#pragma unroll
        for (int i = 0; i < 6; ++i) bias[i] = bias1n[s_g*384 + (ntb + i)*16 + cl];

        const __hip_bfloat16* habase = h0 + ((size_t)s_g*MROWS + b)*128 + rsel*8;
        bf16x8 A[4];
        auto loadA = [&](int tile) {
            int trow = t0 + tile*16 + cl; if (trow < 0) trow = 0;
            const __hip_bfloat16* ap = habase + (size_t)trow*(BATCH*128);
#pragma unroll
            for (int kt = 0; kt < 4; ++kt) A[kt] = *(const bf16x8*)(ap + kt*32);
        };
        auto gemmwrite = [&](int ppw) {
            f32x4 acc[6];
#pragma unroll
            for (int i = 0; i < 6; ++i) acc[i] = (f32x4){bias[i], bias[i], bias[i], bias[i]};
#pragma unroll
            for (int kt = 0; kt < 4; ++kt)
#pragma unroll
                for (int i = 0; i < 6; ++i)
                    acc[i] = __builtin_amdgcn_mfma_f32_16x16x32_bf16(A[kt], Bfr[i][kt], acc[i], 0, 0, 0);
            if (hwr) {   // stage residuals: A-frags ARE h0 values (bf16 pairs)
#pragma unroll
                for (int kt = 0; kt < 4; ++kt) {
                    uint4 aw = __builtin_bit_cast(uint4, A[kt]);
                    unsigned int* hrow = &hstg[ppw][s_g][cl][0];
                    hrow[(rsel*4 + kt*16 + 0) ^ cl] = aw.x;
                    hrow[(rsel*4 + kt*16 + 1) ^ cl] = aw.y;
                    hrow[(rsel*4 + kt*16 + 2) ^ cl] = aw.z;
                    hrow[(rsel*4 + kt*16 + 3) ^ cl] = aw.w;
                }
            }
#pragma unroll
            for (int i = 0; i < 6; ++i) {
                int col = (ntb + i)*16 + cl;
#pragma unroll
                for (int j = 0; j < 4; ++j)
                    ush[ppw][s_g][rsel*4 + j][col] = acc[i][j];
            }
        };
        // prologue: tile 0 into pp=0, then prefetch tile 1
        loadA(0);
        gemmwrite(0);
        loadA(1);
        for (int tile = 0; tile < NTIL; ++tile) {
            __syncthreads();
            if (tile + 1 < NTIL) {
                gemmwrite(pp ^ 1);             // u/h for tile+1 (A holds tile+1)
                int tn = tile + 2; if (tn > NTIL - 1) tn = NTIL - 1;
                loadA(tn);                      // drained at NEXT barrier (hidden)
            }
            pp ^= 1;
        }
    } else {
        // ================= scan role =================
        int s_s = wid >> 1, half = wid & 1, d = half*64 + lane;
        const float* v1s = s_s ? bv1 : av1;
        float vf2 = -L2E * v1s[d], vr2 = -L2E * v1s[128 + d];
        float wl = Wlast[d];
        float cst = 0.f;
        float* pb = pbuf + ((size_t)wid*BATCH + b)*T_LEN;
        int dsw = d >> 1, dodd = lane & 1;

        for (int tile = 0; tile < NTIL; ++tile) {
            __syncthreads();
            int tt0 = t0 + tile*16;
#pragma unroll
            for (int h8 = 0; h8 < 2; ++h8) {
                float u0v[8], u1v[8], u2v[8], rv[8], hv[8];
#pragma unroll
                for (int k = 0; k < 8; ++k) {
                    int tt = h8*8 + k;
                    const float* ur = &ush[pp][s_s][tt][0];
                    u0v[k] = ur[d]; u1v[k] = ur[128 + d]; u2v[k] = ur[256 + d];
                    unsigned int w = hstg[pp][s_s][tt][dsw ^ tt];
                    unsigned int hb = dodd ? (w >> 16) : (w & 0xffffu);
                    rv[k] = __uint_as_float(hb << 16);
                    if (tt0 + tt < 0) u1v[k] = -__builtin_inff();  // keep cst (chunk 0 pad)
                }
#pragma unroll
                for (int k = 0; k < 8; ++k) {
                    float e  = __builtin_amdgcn_exp2f(fmaf(vf2, cst, u1v[k]));
                    float g  = __builtin_amdgcn_rcpf(e + 1.0f);
                    float cn = fmaf(g, cst - u0v[k], u0v[k]);
                    float er = __builtin_amdgcn_exp2f(fmaf(vr2, cn, u2v[k]));
                    float rr = __builtin_amdgcn_rcpf(er + 1.0f);
                    float sr = SQRT2 * rv[k];
                    hv[k] = fmaf(rr, cn - sr, sr);
                    cst = cn;
                }
                // hoisted W_last reduce: 8 sums across 64 lanes
                float pr[8];
#pragma unroll
                for (int k = 0; k < 8; ++k) {
                    float p = wl * hv[k];
                    p += __shfl_xor(p, 32);
                    p += __shfl_xor(p, 16);
                    p += __shfl_xor(p, 8);
                    pr[k] = p;   // partial over lanes == lane (mod 8)
                }
                int g3 = lane >> 3;
                float a0 = (g3 & 1) ? pr[1] : pr[0];
                float a1 = (g3 & 1) ? pr[3] : pr[2];
                float a2 = (g3 & 1) ? pr[5] : pr[4];
                float a3 = (g3 & 1) ? pr[7] : pr[6];
                float b0 = (g3 & 2) ? a1 : a0;
                float b1 = (g3 & 2) ? a3 : a2;
                float q  = (g3 & 4) ? b1 : b0;
                q += __shfl_xor(q, 1);
                q += __shfl_xor(q, 2);
                q += __shfl_xor(q, 4);
                int tsel = tt0 + h8*8 + g3;
                if ((lane & 7) == 0 && tsel >= tw) pb[tsel] = q;
            }
            pp ^= 1;
        }
    }
}

// ---------------------------------------------------------------------------
// finalk: out[b][t] = b_last + sum over 4 partial slots
// ---------------------------------------------------------------------------
__global__ void finalk(const float* __restrict__ pbuf, const float* __restrict__ blast,
                       float* __restrict__ out) {
    int idx = blockIdx.x*256 + threadIdx.x;
    if (idx >= BATCH*T_LEN) return;
    int b = idx / T_LEN, t = idx - b*T_LEN;
    float v = blast[0];
#pragma unroll
    for (int k = 0; k < 4; ++k) v += pbuf[((size_t)k*BATCH + b)*T_LEN + t];
    out[idx] = v;
}

// ---------------------------------------------------------------------------
extern "C" void kernel_launch(void* const* d_in, const int* in_sizes, int n_in,
                              void* d_out, int out_size, void* d_ws, size_t ws_size,
                              hipStream_t stream) {
    const float* tensor = (const float*)d_in[0];
    const float* Wfirst = (const float*)d_in[1];
    const float* bfirst = (const float*)d_in[2];
    const float* Wlast  = (const float*)d_in[3];
    const float* blast  = (const float*)d_in[4];
    const float* aW0 = (const float*)d_in[5];
    const float* av0 = (const float*)d_in[6];
    const float* ab0 = (const float*)d_in[7];
    const float* aW1 = (const float*)d_in[8];
    const float* av1 = (const float*)d_in[9];
    const float* ab1 = (const float*)d_in[10];
    const float* bW0 = (const float*)d_in[11];
    const float* bv0 = (const float*)d_in[12];
    const float* bb0 = (const float*)d_in[13];
    const float* bW1 = (const float*)d_in[14];
    const float* bv1 = (const float*)d_in[15];
    const float* bb1 = (const float*)d_in[16];
    float* out = (float*)d_out;

    char* ws = (char*)d_ws;
    size_t off = 0;
    float* Mn     = (float*)(ws + off); off += 2*9*4*128*sizeof(float);
    float* biasn  = (float*)(ws + off); off += 2*4*128*sizeof(float);
    float* bias1n = (float*)(ws + off); off += 2*384*sizeof(float);
    off = (off + 255) & ~(size_t)255;
    __hip_bfloat16* Bpack = (__hip_bfloat16*)(ws + off); off += (size_t)2*24*4*64*8*2;
    off = (off + 255) & ~(size_t)255;
    float* pbuf = (float*)(ws + off); off += (size_t)4*BATCH*T_LEN*sizeof(float);
    off = (off + 255) & ~(size_t)255;
    __hip_bfloat16* h0 = (__hip_bfloat16*)(ws + off); off += (size_t)2*MROWS*128*2;
    (void)ws_size; (void)in_sizes; (void)n_in; (void)out_size;
    // total workspace: ~135.4 MB

    prep_misc<<<dim3(2, 4), 128, 0, stream>>>(Wfirst, bfirst, aW0, bW0, ab0, bb0, ab1, bb1,
                                              Mn, biasn, bias1n);
    prep_bpack<<<dim3(24, 2), 256, 0, stream>>>(aW1, bW1, Bpack);
    scan0<<<dim3(KCH0, BATCH), 256, 0, stream>>>(tensor, av0, bv0, Mn, biasn, h0);
    scan1f<<<dim3(KCH1, BATCH), 768, 0, stream>>>(h0, Bpack, bias1n, av1, bv1, Wlast, pbuf);
    finalk<<<dim3((BATCH*T_LEN + 255)/256), 256, 0, stream>>>(pbuf, blast, out);
}

// Round 7
// 427.093 us; speedup vs baseline: 1.9723x; 1.0708x over previous
//
#include <hip/hip_runtime.h>
#include <hip/hip_bf16.h>

#define L2E   1.44269504088896340736f
#define SQRT2 1.41421356237309504880f

#define T_LEN 32000
#define BATCH 8
#define NCH   9

// scan0 chunking
#define KCH0  125
#define CL0   256
#define WU    128      // layer-0 warm-up (nsteps 384 or 256, both /4)
// scan1f chunking
#define KCH1  32
#define CL1   1000
#define WUF   136      // layer-1 warm-up; (CL1+WUF)=1136=71*16
#define NTIL  71

#define MROWS (T_LEN*BATCH)   // 256000 rows per stack

typedef __bf16 bf16x8 __attribute__((ext_vector_type(8)));
typedef float  f32x4  __attribute__((ext_vector_type(4)));
typedef float  f32x2  __attribute__((ext_vector_type(2)));

// ---------------------------------------------------------------------------
// prep_misc v2: stage Wf+bfirst in LDS, single fused unrolled i-loop.
// grid(2,4): s = x, gate = y; block(128) = one thread per d.
// ---------------------------------------------------------------------------
__global__ __launch_bounds__(128) void prep_misc(const float* __restrict__ Wf,
                          const float* __restrict__ bfirst,
                          const float* __restrict__ aW0, const float* __restrict__ bW0,
                          const float* __restrict__ ab0, const float* __restrict__ bb0,
                          const float* __restrict__ ab1, const float* __restrict__ bb1,
                          float* __restrict__ Mn, float* __restrict__ biasn,
                          float* __restrict__ bias1n) {
    __shared__ float WfL[64][10];   // [i][c<9]=Wf, [i][9]=bfirst
    int s = blockIdx.x, g = blockIdx.y;
    int d = threadIdx.x;  // 0..127
    const float* W0s = s ? bW0 : aW0;
    const float* b0s = s ? bb0 : ab0;
    const float* b1s = s ? bb1 : ab1;

    for (int idx = d; idx < 640; idx += 128) {
        int i = idx / 10, c = idx - i*10;
        WfL[i][c] = (c < NCH) ? Wf[(s*64 + i)*NCH + c] : bfirst[s*64 + i];
    }
    __syncthreads();

    float acc[10];
#pragma unroll
    for (int c = 0; c < 10; ++c) acc[c] = 0.f;
#pragma unroll 8
    for (int i = 0; i < 64; ++i) {
        float w = W0s[i*512 + g*128 + d];
#pragma unroll
        for (int c = 0; c < 10; ++c) acc[c] = fmaf(w, WfL[i][c], acc[c]);
    }
    float scale = (g == 1 || g == 2) ? -L2E : (g == 3 ? SQRT2 : 1.0f);
#pragma unroll
    for (int c = 0; c < NCH; ++c)
        Mn[((s*NCH + c)*4 + g)*128 + d] = scale * acc[c];
    float bb = acc[9];
    if (g == 1) bb += b0s[d];
    if (g == 2) bb += b0s[128 + d];
    biasn[(s*4 + g)*128 + d] = scale * bb;

    if (g == 0) {
        bias1n[s*384 + d      ] = 0.0f;
        bias1n[s*384 + 128 + d] = -L2E * b1s[d];
        bias1n[s*384 + 256 + d] = -L2E * b1s[128 + d];
    }
}

// ---------------------------------------------------------------------------
// prep_bpack: pack W1 (128x384 fp32) into MFMA B-fragment order, bf16, with
// -log2e folded into columns 128..383.
// Bpack[s][nt(24)][kt(4)][lane(64)][jj(8)];
// frag: lane holds B[k=kt*32+(lane>>4)*8+jj][n=nt*16+(lane&15)]
// grid(24,2), block(256)
// ---------------------------------------------------------------------------
__global__ void prep_bpack(const float* __restrict__ aW1, const float* __restrict__ bW1,
                           __hip_bfloat16* __restrict__ Bpack) {
    int nt = blockIdx.x, s = blockIdx.y;
    int kt = threadIdx.x >> 6, lane = threadIdx.x & 63;
    const float* W1s = s ? bW1 : aW1;
    int n = nt*16 + (lane & 15);
    float csc = (n < 128) ? 1.0f : -L2E;
    for (int jj = 0; jj < 8; ++jj) {
        int k = kt*32 + (lane >> 4)*8 + jj;
        Bpack[((size_t)((s*24 + nt)*4 + kt)*64 + lane)*8 + jj] =
            __float2bfloat16(csc * W1s[k*384 + n]);
    }
}

// ---------------------------------------------------------------------------
// scan0: fused input-conv (folded Mn) + layer-0 SRU scan.
// grid(KCH0, 8), block(256): 4 waves = (stack, half). 3 blocks/CU; VGPR cap
// 170 so the ~95-reg live set cannot spill.
// ---------------------------------------------------------------------------
__global__ __launch_bounds__(256, 3) void scan0(const float* __restrict__ tensor,
        const float* __restrict__ av0, const float* __restrict__ bv0,
        const float* __restrict__ Mn, const float* __restrict__ biasn,
        __hip_bfloat16* __restrict__ h0) {
    __shared__ __align__(16) float ldsx[(CL0 + WU) * 12];
    int chunk = blockIdx.x, b = blockIdx.y;
    int tid = threadIdx.x, wid = tid >> 6, lane = tid & 63;
    int s = wid >> 1, half = wid & 1, d = half*64 + lane;

    int t0 = chunk*CL0 - WU; if (t0 < 0) t0 = 0;
    int tend = (chunk + 1)*CL0;
    int nsteps = tend - t0;          // 384 or 256, both /4, ngrp even

    for (int c = 0; c < NCH; ++c) {
        const float* src = tensor + ((size_t)b*NCH + c)*T_LEN + t0;
        for (int j = tid; j < nsteps; j += 256) ldsx[j*12 + c] = src[j];
    }
    __syncthreads();

    f32x2 M01[NCH], M23[NCH], b01, b23;
    {
        float M[4][NCH], bi[4];
#pragma unroll
        for (int g = 0; g < 4; ++g) {
            bi[g] = biasn[(s*4 + g)*128 + d];
#pragma unroll
            for (int c = 0; c < NCH; ++c) M[g][c] = Mn[((s*NCH + c)*4 + g)*128 + d];
        }
#pragma unroll
        for (int c = 0; c < NCH; ++c) {
            M01[c] = (f32x2){M[0][c], M[1][c]};
            M23[c] = (f32x2){M[2][c], M[3][c]};
        }
        b01 = (f32x2){bi[0], bi[1]};
        b23 = (f32x2){bi[2], bi[3]};
    }
    const float* v0s = s ? bv0 : av0;
    float vf2 = -L2E * v0s[d];
    float vr2 = -L2E * v0s[128 + d];

    float cst = 0.f;
    int hw_off = chunk*CL0 - t0;     // first step index to store (0 or WU)
    __hip_bfloat16* hbase = h0 + ((size_t)s*MROWS + b)*128 + d;

    auto compU = [&](int grp, f32x2* u01v, f32x2* u23v) {
#pragma unroll
        for (int k = 0; k < 4; ++k) {
            const float* xr = ldsx + (grp*4 + k)*12;
            float4 xlo = *(const float4*)xr;
            float4 xhi = *(const float4*)(xr + 4);
            float x8 = xr[8];
            f32x2 a = b01, c2 = b23;
            a += M01[0]*xlo.x; c2 += M23[0]*xlo.x;
            a += M01[1]*xlo.y; c2 += M23[1]*xlo.y;
            a += M01[2]*xlo.z; c2 += M23[2]*xlo.z;
            a += M01[3]*xlo.w; c2 += M23[3]*xlo.w;
            a += M01[4]*xhi.x; c2 += M23[4]*xhi.x;
            a += M01[5]*xhi.y; c2 += M23[5]*xhi.y;
            a += M01[6]*xhi.z; c2 += M23[6]*xhi.z;
            a += M01[7]*xhi.w; c2 += M23[7]*xhi.w;
            a += M01[8]*x8;    c2 += M23[8]*x8;
            u01v[k] = a; u23v[k] = c2;
        }
    };
    auto chain = [&](f32x2* u01v, f32x2* u23v, int grp) {
#pragma unroll
        for (int k = 0; k < 4; ++k) {
            float e  = __builtin_amdgcn_exp2f(fmaf(vf2, cst, u01v[k].y));
            float g  = __builtin_amdgcn_rcpf(e + 1.0f);
            float cn = fmaf(g, cst - u01v[k].x, u01v[k].x);
            float er = __builtin_amdgcn_exp2f(fmaf(vr2, cn, u23v[k].x));
            float rr = __builtin_amdgcn_rcpf(er + 1.0f);
            float h  = fmaf(rr, cn - u23v[k].y, u23v[k].y);
            cst = cn;
            int j = grp*4 + k;
            if (j >= hw_off) hbase[(size_t)(t0 + j)*(BATCH*128)] = __float2bfloat16(h);
        }
    };

    f32x2 uA01[4], uA23[4], uB01[4], uB23[4];
    int ngrp = nsteps >> 2;
    compU(0, uA01, uA23);
    int g = 0;
    while (g + 2 <= ngrp) {
        compU(g + 1, uB01, uB23);
        chain(uA01, uA23, g);
        if (g + 2 < ngrp) compU(g + 2, uA01, uA23);
        chain(uB01, uB23, g + 1);
        g += 2;
    }
}

// ---------------------------------------------------------------------------
// scan1f v3: fused layer-1 GEMM + SRU scan + W_last proj, producer/consumer.
// grid(KCH1, 8), block(1024) = 16 waves:
//   waves 0-3  : scan-only (stack = wid>>1, half = wid&1), s_setprio(1)
//   waves 4-15 : GEMM-only. gw = wid-4 in 0..11; s_g = gw/6; 4 N-tiles each.
// One barrier per tile; ping-pong ush/hstg. A-fragments double-buffered in
// registers (Aa/Ab, statically named via 2x-unrolled tile loop) so the global
// load issued in iter t is consumed in iter t+1 -- a full gemmwrite plus a
// barrier of covering work, no exposed drain. acc streamed per-nt to keep the
// GEMM live set ~120 VGPR (< the 128 cap of launch_bounds(1024,4)).
// ---------------------------------------------------------------------------
__global__ __launch_bounds__(1024, 4) void scan1f(const __hip_bfloat16* __restrict__ h0,
        const __hip_bfloat16* __restrict__ Bpack, const float* __restrict__ bias1n,
        const float* __restrict__ av1, const float* __restrict__ bv1,
        const float* __restrict__ Wlast, float* __restrict__ pbuf) {
    __shared__ __align__(16) float ush[2][2][16][388];       // 99,328 B
    __shared__ unsigned int hstg[2][2][16][64];              // 16,384 B
    int chunk = blockIdx.x, b = blockIdx.y;
    int tid = threadIdx.x, wid = tid >> 6, lane = tid & 63;
    int cl = lane & 15, rsel = lane >> 4;
    int tw = chunk*CL1, t0 = tw - WUF;   // negative for chunk 0
    int pp = 0;

    if (wid >= 4) {
        // ================= GEMM role =================
        int gw = wid - 4;                  // 0..11
        int s_g = (gw >= 6) ? 1 : 0;
        int ntb = (gw - s_g*6) * 4;        // 0,4,8,12,16,20
        bool hwr = (ntb == 0);             // one wave per stack stages residuals
        bf16x8 Bfr[4][4];
        const bf16x8* bsrc = (const bf16x8*)Bpack;
#pragma unroll
        for (int i = 0; i < 4; ++i)
#pragma unroll
            for (int kt = 0; kt < 4; ++kt)
                Bfr[i][kt] = bsrc[((s_g*24 + ntb + i)*4 + kt)*64 + lane];
        float bias[4];
#pragma unroll
        for (int i = 0; i < 4; ++i) bias[i] = bias1n[s_g*384 + (ntb + i)*16 + cl];

        const __hip_bfloat16* habase = h0 + ((size_t)s_g*MROWS + b)*128 + rsel*8;
        bf16x8 Aa[4], Ab[4];
        auto loadA = [&](int tile, bf16x8 (&A)[4]) {
            if (tile > NTIL - 1) tile = NTIL - 1;
            int trow = t0 + tile*16 + cl; if (trow < 0) trow = 0;
            const __hip_bfloat16* ap = habase + (size_t)trow*(BATCH*128);
#pragma unroll
            for (int kt = 0; kt < 4; ++kt) A[kt] = *(const bf16x8*)(ap + kt*32);
        };
        auto gemmwrite = [&](int ppw, bf16x8 (&A)[4]) {
#pragma unroll
            for (int i = 0; i < 4; ++i) {
                f32x4 acc = (f32x4){bias[i], bias[i], bias[i], bias[i]};
#pragma unroll
                for (int kt = 0; kt < 4; ++kt)
                    acc = __builtin_amdgcn_mfma_f32_16x16x32_bf16(A[kt], Bfr[i][kt], acc, 0, 0, 0);
                int col = (ntb + i)*16 + cl;
#pragma unroll
                for (int j = 0; j < 4; ++j)
                    ush[ppw][s_g][rsel*4 + j][col] = acc[j];
            }
            if (hwr) {   // stage residuals: A-frags ARE h0 values (bf16 pairs)
#pragma unroll
                for (int kt = 0; kt < 4; ++kt) {
                    uint4 aw = __builtin_bit_cast(uint4, A[kt]);
                    unsigned int* hrow = &hstg[ppw][s_g][cl][0];
                    hrow[(rsel*4 + kt*16 + 0) ^ cl] = aw.x;
                    hrow[(rsel*4 + kt*16 + 1) ^ cl] = aw.y;
                    hrow[(rsel*4 + kt*16 + 2) ^ cl] = aw.z;
                    hrow[(rsel*4 + kt*16 + 3) ^ cl] = aw.w;
                }
            }
        };
        // prologue: tile 0 via Aa into pp=0, tile 1 prefetched into Ab
        loadA(0, Aa);
        gemmwrite(0, Aa);
        loadA(1, Ab);
        // 2x-unrolled pipeline: even iter consumes Ab & refills Aa, odd the
        // converse. Load->use distance = one gemmwrite + one barrier.
        for (int tile = 0; tile < NTIL - 1; tile += 2) {
            __syncthreads();
            loadA(tile + 2, Aa);
            gemmwrite(pp ^ 1, Ab);           // tile+1
            pp ^= 1;
            __syncthreads();
            loadA(tile + 3, Ab);
            if (tile + 2 < NTIL) gemmwrite(pp ^ 1, Aa);   // tile+2
            pp ^= 1;
        }
        __syncthreads();                     // iter tile = NTIL-1: no work
    } else {
        // ================= scan role =================
        __builtin_amdgcn_s_setprio(1);
        int s_s = wid >> 1, half = wid & 1, d = half*64 + lane;
        const float* v1s = s_s ? bv1 : av1;
        float vf2 = -L2E * v1s[d], vr2 = -L2E * v1s[128 + d];
        float wl = Wlast[d];
        float cst = 0.f;
        float* pb = pbuf + ((size_t)wid*BATCH + b)*T_LEN;
        int dsw = d >> 1, dodd = lane & 1;

        for (int tile = 0; tile < NTIL; ++tile) {
            __syncthreads();
            int tt0 = t0 + tile*16;
#pragma unroll
            for (int h8 = 0; h8 < 2; ++h8) {
                float u0v[8], u1v[8], u2v[8], rv[8], hv[8];
#pragma unroll
                for (int k = 0; k < 8; ++k) {
                    int tt = h8*8 + k;
                    const float* ur = &ush[pp][s_s][tt][0];
                    u0v[k] = ur[d]; u1v[k] = ur[128 + d]; u2v[k] = ur[256 + d];
                    unsigned int w = hstg[pp][s_s][tt][dsw ^ tt];
                    unsigned int hb = dodd ? (w >> 16) : (w & 0xffffu);
                    rv[k] = __uint_as_float(hb << 16);
                    if (tt0 + tt < 0) u1v[k] = -__builtin_inff();  // keep cst (chunk 0 pad)
                }
#pragma unroll
                for (int k = 0; k < 8; ++k) {
                    float e  = __builtin_amdgcn_exp2f(fmaf(vf2, cst, u1v[k]));
                    float g  = __builtin_amdgcn_rcpf(e + 1.0f);
                    float cn = fmaf(g, cst - u0v[k], u0v[k]);
                    float er = __builtin_amdgcn_exp2f(fmaf(vr2, cn, u2v[k]));
                    float rr = __builtin_amdgcn_rcpf(er + 1.0f);
                    float sr = SQRT2 * rv[k];
                    hv[k] = fmaf(rr, cn - sr, sr);
                    cst = cn;
                }
                // hoisted W_last reduce: 8 sums across 64 lanes
                float pr[8];
#pragma unroll
                for (int k = 0; k < 8; ++k) {
                    float p = wl * hv[k];
                    p += __shfl_xor(p, 32);
                    p += __shfl_xor(p, 16);
                    p += __shfl_xor(p, 8);
                    pr[k] = p;   // partial over lanes == lane (mod 8)
                }
                int g3 = lane >> 3;
                float a0 = (g3 & 1) ? pr[1] : pr[0];
                float a1 = (g3 & 1) ? pr[3] : pr[2];
                float a2 = (g3 & 1) ? pr[5] : pr[4];
                float a3 = (g3 & 1) ? pr[7] : pr[6];
                float b0 = (g3 & 2) ? a1 : a0;
                float b1 = (g3 & 2) ? a3 : a2;
                float q  = (g3 & 4) ? b1 : b0;
                q += __shfl_xor(q, 1);
                q += __shfl_xor(q, 2);
                q += __shfl_xor(q, 4);
                int tsel = tt0 + h8*8 + g3;
                if ((lane & 7) == 0 && tsel >= tw) pb[tsel] = q;
            }
            pp ^= 1;
        }
    }
}

// ---------------------------------------------------------------------------
// finalk: out[b][t] = b_last + sum over 4 partial slots
// ---------------------------------------------------------------------------
__global__ void finalk(const float* __restrict__ pbuf, const float* __restrict__ blast,
                       float* __restrict__ out) {
    int idx = blockIdx.x*256 + threadIdx.x;
    if (idx >= BATCH*T_LEN) return;
    int b = idx / T_LEN, t = idx - b*T_LEN;
    float v = blast[0];
#pragma unroll
    for (int k = 0; k < 4; ++k) v += pbuf[((size_t)k*BATCH + b)*T_LEN + t];
    out[idx] = v;
}

// ---------------------------------------------------------------------------
extern "C" void kernel_launch(void* const* d_in, const int* in_sizes, int n_in,
                              void* d_out, int out_size, void* d_ws, size_t ws_size,
                              hipStream_t stream) {
    const float* tensor = (const float*)d_in[0];
    const float* Wfirst = (const float*)d_in[1];
    const float* bfirst = (const float*)d_in[2];
    const float* Wlast  = (const float*)d_in[3];
    const float* blast  = (const float*)d_in[4];
    const float* aW0 = (const float*)d_in[5];
    const float* av0 = (const float*)d_in[6];
    const float* ab0 = (const float*)d_in[7];
    const float* aW1 = (const float*)d_in[8];
    const float* av1 = (const float*)d_in[9];
    const float* ab1 = (const float*)d_in[10];
    const float* bW0 = (const float*)d_in[11];
    const float* bv0 = (const float*)d_in[12];
    const float* bb0 = (const float*)d_in[13];
    const float* bW1 = (const float*)d_in[14];
    const float* bv1 = (const float*)d_in[15];
    const float* bb1 = (const float*)d_in[16];
    float* out = (float*)d_out;

    char* ws = (char*)d_ws;
    size_t off = 0;
    float* Mn     = (float*)(ws + off); off += 2*9*4*128*sizeof(float);
    float* biasn  = (float*)(ws + off); off += 2*4*128*sizeof(float);
    float* bias1n = (float*)(ws + off); off += 2*384*sizeof(float);
    off = (off + 255) & ~(size_t)255;
    __hip_bfloat16* Bpack = (__hip_bfloat16*)(ws + off); off += (size_t)2*24*4*64*8*2;
    off = (off + 255) & ~(size_t)255;
    float* pbuf = (float*)(ws + off); off += (size_t)4*BATCH*T_LEN*sizeof(float);
    off = (off + 255) & ~(size_t)255;
    __hip_bfloat16* h0 = (__hip_bfloat16*)(ws + off); off += (size_t)2*MROWS*128*2;
    (void)ws_size; (void)in_sizes; (void)n_in; (void)out_size;
    // total workspace: ~135.4 MB

    prep_misc<<<dim3(2, 4), 128, 0, stream>>>(Wfirst, bfirst, aW0, bW0, ab0, bb0, ab1, bb1,
                                              Mn, biasn, bias1n);
    prep_bpack<<<dim3(24, 2), 256, 0, stream>>>(aW1, bW1, Bpack);
    scan0<<<dim3(KCH0, BATCH), 256, 0, stream>>>(tensor, av0, bv0, Mn, biasn, h0);
    scan1f<<<dim3(KCH1, BATCH), 1024, 0, stream>>>(h0, Bpack, bias1n, av1, bv1, Wlast, pbuf);
    finalk<<<dim3((BATCH*T_LEN + 255)/256), 256, 0, stream>>>(pbuf, blast, out);
}